// Round 16
// baseline (1421.069 us; speedup 1.0000x reference)
//
#include <hip/hip_runtime.h>
#include <math.h>

#define B_  64
#define T_  150
#define L_  256
#define H_  512
#define E_  512
#define V_  1000
#define G4_ 2048   // 4*H
#define DB_ 8      // decoder blocks
#define HCB 64     // h-cols per decoder block (DB_*HCB == H_)

typedef _Float16 f16;
typedef f16   f16x8 __attribute__((ext_vector_type(8)));
typedef f16   f16x4 __attribute__((ext_vector_type(4)));
typedef float f32x4 __attribute__((ext_vector_type(4)));
typedef unsigned long long ull;

__device__ __forceinline__ float sigmf(float x) { return 1.0f / (1.0f + expf(-x)); }

// ---------------- fence-free persistent LSTM decoder (MFMA, 8 blocks) ------
// Block bb owns h-cols [bb*64, bb*64+64) -> 256 gate rows (4 gates x 64).
// Wave wv owns N-tiles {2wv, 2wv+1} (of 16), all 4 M-tiles; B-fragments in
// registers (bfr[2][16], same budget as R11). h exchange: 8B relaxed AGENT
// atomics (coherence-point, no fences) - aggregate traffic halved vs R11.
__global__ __launch_bounds__(512) void decoder_mfma(
    const int*   __restrict__ seq,    // [B][T]
    const float* __restrict__ G,      // [V][4H] pregate table
    const float* __restrict__ Whh,    // [4H][H] fp32
    ull*  __restrict__ xh,            // [2][64][128] packed fp16 x4
    int*  __restrict__ tags,          // [8] monotone step tags
    float* __restrict__ hbuf)         // rows (t,b): [T*B][H]
{
    __shared__ f16   hlds[64][520];    // h fp16, 66.6 KB
    __shared__ float glds[64][260];    // gates fp32 [b][256+pad], 66.6 KB
    __shared__ float csh[64][68];      // c-state [b][64+pad], 17.4 KB

    const int tid = threadIdx.x;
    const int bb  = blockIdx.x;
    const int ln  = tid & 63;
    const int wv  = tid >> 6;          // 0..7: N-tiles {2wv, 2wv+1}
    const int ln15 = ln & 15;
    const int lnk8 = (ln >> 4) * 8;
    const int lr4  = (ln >> 4) * 4;

    // ---- one-time: B fragments global -> registers (fp32 -> fp16)
    // N-tile n (0..15): gate q = n>>2, jj-base = (n&3)*16.
    f16x8 bfr[2][16];
    #pragma unroll
    for (int j = 0; j < 2; ++j) {
        const int n = 2 * wv + j;
        const int grow = (n >> 2) * H_ + bb * HCB + (n & 3) * 16 + ln15;
        #pragma unroll
        for (int kt = 0; kt < 16; ++kt) {
            const int k0 = kt * 32 + lnk8;
            float4 w0 = *(const float4*)(Whh + (size_t)grow * H_ + k0);
            float4 w1 = *(const float4*)(Whh + (size_t)grow * H_ + k0 + 4);
            bfr[j][kt] = (f16x8){(f16)w0.x, (f16)w0.y, (f16)w0.z, (f16)w0.w,
                                 (f16)w1.x, (f16)w1.y, (f16)w1.z, (f16)w1.w};
        }
    }
    // zero hlds / csh
    for (int e = tid; e < 64 * 520 / 4; e += 512) ((ull*)hlds)[e] = 0ull;
    for (int e = tid; e < 64 * 68; e += 512) ((float*)csh)[e] = 0.f;
    __syncthreads();

    const int cb = tid >> 3, cg = tid & 7;   // cell role: b, 8-col group

    for (int t = 0; t < T_; ++t) {
        // ---- G prefetch for THIS step (independent of h; hides under poll)
        const int v = seq[cb * T_ + t];
        const float* gp = G + (size_t)v * G4_ + bb * HCB + cg * 8;
        float4 ga[4][2];
        #pragma unroll
        for (int q = 0; q < 4; ++q) {
            ga[q][0] = *(const float4*)(gp + q * H_);
            ga[q][1] = *(const float4*)(gp + q * H_ + 4);
        }

        if (t > 0) {
            if (tid < DB_) {
                while (__hip_atomic_load(&tags[tid], __ATOMIC_RELAXED,
                                         __HIP_MEMORY_SCOPE_AGENT) < t) {}
            }
            __syncthreads();
            // ---- bulk-load h^t: reg-stage 16 x 8B loads, then 8 x b128 writes
            const ull* src = xh + (size_t)(t & 1) * 64 * 128;
            ull v0[8], v1[8];
            #pragma unroll
            for (int it = 0; it < 8; ++it) {
                const int e = tid + it * 512;
                const int b = e >> 6, s = e & 63;
                v0[it] = __hip_atomic_load(&src[b * 128 + 2 * s], __ATOMIC_RELAXED,
                                           __HIP_MEMORY_SCOPE_AGENT);
                v1[it] = __hip_atomic_load(&src[b * 128 + 2 * s + 1], __ATOMIC_RELAXED,
                                           __HIP_MEMORY_SCOPE_AGENT);
            }
            #pragma unroll
            for (int it = 0; it < 8; ++it) {
                const int e = tid + it * 512;
                const int b = e >> 6, s = e & 63;
                ull* dst = (ull*)&hlds[b][s * 8];
                dst[0] = v0[it]; dst[1] = v1[it];
            }
            __syncthreads();
        }

        // ---- gate GEMM: 4 M-tiles x 2 N-tiles per wave, K=512
        f32x4 acc[4][2] = {};
        #pragma unroll
        for (int kt = 0; kt < 16; ++kt) {
            const int ko = kt * 32 + lnk8;
            f16x8 a0 = *(const f16x8*)&hlds[0 * 16 + ln15][ko];
            f16x8 a1 = *(const f16x8*)&hlds[1 * 16 + ln15][ko];
            f16x8 a2 = *(const f16x8*)&hlds[2 * 16 + ln15][ko];
            f16x8 a3 = *(const f16x8*)&hlds[3 * 16 + ln15][ko];
            #pragma unroll
            for (int j = 0; j < 2; ++j) {
                acc[0][j] = __builtin_amdgcn_mfma_f32_16x16x32_f16(a0, bfr[j][kt], acc[0][j], 0, 0, 0);
                acc[1][j] = __builtin_amdgcn_mfma_f32_16x16x32_f16(a1, bfr[j][kt], acc[1][j], 0, 0, 0);
                acc[2][j] = __builtin_amdgcn_mfma_f32_16x16x32_f16(a2, bfr[j][kt], acc[2][j], 0, 0, 0);
                acc[3][j] = __builtin_amdgcn_mfma_f32_16x16x32_f16(a3, bfr[j][kt], acc[3][j], 0, 0, 0);
            }
        }
        // C/D layout: col = lane&15, row = (lane>>4)*4 + reg
        #pragma unroll
        for (int m = 0; m < 4; ++m)
            #pragma unroll
            for (int j = 0; j < 2; ++j)
                #pragma unroll
                for (int i = 0; i < 4; ++i)
                    glds[m * 16 + lr4 + i][(2 * wv + j) * 16 + ln15] = acc[m][j][i];
        __syncthreads();

        // ---- cell: thread (cb, cols cg*8..cg*8+7); publish 2x8B
        {
            float gi[8], gf[8], gg[8], go[8], cl[8];
            #pragma unroll
            for (int hh = 0; hh < 2; ++hh) {
                float4 Gi = *(const float4*)&glds[cb][0 * 64 + cg * 8 + hh * 4];
                float4 Gf = *(const float4*)&glds[cb][1 * 64 + cg * 8 + hh * 4];
                float4 Gg = *(const float4*)&glds[cb][2 * 64 + cg * 8 + hh * 4];
                float4 Go = *(const float4*)&glds[cb][3 * 64 + cg * 8 + hh * 4];
                float4 cc = *(const float4*)&csh[cb][cg * 8 + hh * 4];
                #pragma unroll
                for (int i = 0; i < 4; ++i) {
                    gi[hh * 4 + i] = ((const float*)&Gi)[i] + ((const float*)&ga[0][hh])[i];
                    gf[hh * 4 + i] = ((const float*)&Gf)[i] + ((const float*)&ga[1][hh])[i];
                    gg[hh * 4 + i] = ((const float*)&Gg)[i] + ((const float*)&ga[2][hh])[i];
                    go[hh * 4 + i] = ((const float*)&Go)[i] + ((const float*)&ga[3][hh])[i];
                    cl[hh * 4 + i] = ((const float*)&cc)[i];
                }
            }
            float hv[8], cv[8];
            f16x8 hp;
            #pragma unroll
            for (int i = 0; i < 8; ++i) {
                float c2 = sigmf(gf[i]) * cl[i] + sigmf(gi[i]) * tanhf(gg[i]);
                float h2 = sigmf(go[i]) * tanhf(c2);
                cv[i] = c2; hv[i] = h2; hp[i] = (f16)h2;
            }
            *(float4*)&csh[cb][cg * 8]     = make_float4(cv[0], cv[1], cv[2], cv[3]);
            *(float4*)&csh[cb][cg * 8 + 4] = make_float4(cv[4], cv[5], cv[6], cv[7]);
            float* hb = hbuf + ((size_t)t * 64 + cb) * H_ + bb * HCB + cg * 8;
            *(float4*)hb       = make_float4(hv[0], hv[1], hv[2], hv[3]);
            *(float4*)(hb + 4) = make_float4(hv[4], hv[5], hv[6], hv[7]);
            ull* dst = &xh[(size_t)((t + 1) & 1) * 64 * 128 + cb * 128 + bb * 16 + cg * 2];
            __hip_atomic_store(&dst[0], ((const ull*)&hp)[0],
                               __ATOMIC_RELAXED, __HIP_MEMORY_SCOPE_AGENT);
            __hip_atomic_store(&dst[1], ((const ull*)&hp)[1],
                               __ATOMIC_RELAXED, __HIP_MEMORY_SCOPE_AGENT);
        }
        __syncthreads();   // compiler drains vmcnt before s_barrier
        if (tid == 0)
            __hip_atomic_store(&tags[bb], t + 1, __ATOMIC_RELAXED,
                               __HIP_MEMORY_SCOPE_AGENT);
    }
}

// ---------------- fp16-MFMA NT GEMM: C[M][N] = op([A1|A2])[M][K] @ Bm[N][K]^T
template<bool RELU_A, bool REMAP>
__global__ __launch_bounds__(256) void gemm16_nt(
    const float* __restrict__ A1, const float* __restrict__ A2,
    const float* __restrict__ Bm,
    const float* __restrict__ bias1, const float* __restrict__ bias2,
    float* __restrict__ C, int M, int N, int KA)
{
    __shared__ f16 As[64][40];
    __shared__ f16 Bs[64][40];
    const int tid = threadIdx.x;
    const int m0 = blockIdx.x * 64, n0 = blockIdx.y * 64;
    const int ln = tid & 63, wv = tid >> 6;
    const int lr = tid >> 2, lc8 = (tid & 3) * 8;
    const int K = A2 ? 2 * KA : KA;
    f32x4 acc[4] = {};

    for (int kb = 0; kb < K; kb += 32) {
        const float* Ap; int kk;
        if (kb < KA) { Ap = A1; kk = kb; } else { Ap = A2; kk = kb - KA; }
        int gm = m0 + lr;
        float4 a0 = make_float4(0.f, 0.f, 0.f, 0.f), a1 = a0;
        if (gm < M) {
            a0 = *(const float4*)(Ap + (size_t)gm * KA + kk + lc8);
            a1 = *(const float4*)(Ap + (size_t)gm * KA + kk + lc8 + 4);
        }
        if (RELU_A) {
            a0.x = fmaxf(a0.x, 0.f); a0.y = fmaxf(a0.y, 0.f);
            a0.z = fmaxf(a0.z, 0.f); a0.w = fmaxf(a0.w, 0.f);
            a1.x = fmaxf(a1.x, 0.f); a1.y = fmaxf(a1.y, 0.f);
            a1.z = fmaxf(a1.z, 0.f); a1.w = fmaxf(a1.w, 0.f);
        }
        f16x8 av = {(f16)a0.x, (f16)a0.y, (f16)a0.z, (f16)a0.w,
                    (f16)a1.x, (f16)a1.y, (f16)a1.z, (f16)a1.w};
        *(f16x8*)&As[lr][lc8] = av;

        int gn = n0 + lr;
        float4 b0 = make_float4(0.f, 0.f, 0.f, 0.f), b1 = b0;
        if (gn < N) {
            b0 = *(const float4*)(Bm + (size_t)gn * K + kb + lc8);
            b1 = *(const float4*)(Bm + (size_t)gn * K + kb + lc8 + 4);
        }
        f16x8 bv = {(f16)b0.x, (f16)b0.y, (f16)b0.z, (f16)b0.w,
                    (f16)b1.x, (f16)b1.y, (f16)b1.z, (f16)b1.w};
        *(f16x8*)&Bs[lr][lc8] = bv;
        __syncthreads();

        f16x8 af = *(const f16x8*)&As[wv * 16 + (ln & 15)][(ln >> 4) * 8];
        #pragma unroll
        for (int ntt = 0; ntt < 4; ++ntt) {
            f16x8 bf = *(const f16x8*)&Bs[ntt * 16 + (ln & 15)][(ln >> 4) * 8];
            acc[ntt] = __builtin_amdgcn_mfma_f32_16x16x32_f16(af, bf, acc[ntt], 0, 0, 0);
        }
        __syncthreads();
    }

    #pragma unroll
    for (int ntt = 0; ntt < 4; ++ntt)
        #pragma unroll
        for (int i = 0; i < 4; ++i) {
            int gm = m0 + wv * 16 + (ln >> 4) * 4 + i;
            int gn = n0 + ntt * 16 + (ln & 15);
            if (gm < M && gn < N) {
                float v = acc[ntt][i];
                if (bias1) v += bias1[gn];
                if (bias2) v += bias2[gn];
                size_t row = REMAP ? ((size_t)(gm & 63) * T_ + (gm >> 6)) : (size_t)gm;
                C[row * (size_t)N + gn] = v;
            }
        }
}

// ---------------- fused score GEMM + softmax: per (t-chunk, b)
__global__ __launch_bounds__(512) void score_softmax(
    const float* __restrict__ mapped,  // rows (t,b), stride H
    const float* __restrict__ cnn,     // [B][L][H]
    f16* __restrict__ attP)            // [B][T][L] fp16 probabilities
{
    __shared__ f16   As[64][40];
    __shared__ f16   Bs[256][40];
    __shared__ float sl[64][260];

    const int tid = threadIdx.x;
    const int m0  = blockIdx.x * 64;
    const int b   = blockIdx.y;
    const int ln  = tid & 63, wv = tid >> 6;
    const int mh  = wv >> 2, nq = wv & 3;
    const int ln15 = ln & 15, ln4 = (ln >> 4) * 8;
    const float* cnnb = cnn + (size_t)b * L_ * H_;

    f32x4 acc[2][4] = {};

    for (int kb = 0; kb < H_; kb += 32) {
        {
            int lr = tid >> 3, lc4 = (tid & 7) * 4;
            int t = m0 + lr;
            float4 a = make_float4(0.f, 0.f, 0.f, 0.f);
            if (t < T_) a = *(const float4*)(mapped + ((size_t)t * 64 + b) * H_ + kb + lc4);
            As[lr][lc4 + 0] = (f16)a.x; As[lr][lc4 + 1] = (f16)a.y;
            As[lr][lc4 + 2] = (f16)a.z; As[lr][lc4 + 3] = (f16)a.w;
        }
        {
            int br = tid >> 1, bc16 = (tid & 1) * 16;
            const float* src = cnnb + (size_t)br * H_ + kb + bc16;
            float4 w0 = *(const float4*)(src);
            float4 w1 = *(const float4*)(src + 4);
            float4 w2 = *(const float4*)(src + 8);
            float4 w3 = *(const float4*)(src + 12);
            f16x8 p0 = {(f16)w0.x, (f16)w0.y, (f16)w0.z, (f16)w0.w,
                        (f16)w1.x, (f16)w1.y, (f16)w1.z, (f16)w1.w};
            f16x8 p1 = {(f16)w2.x, (f16)w2.y, (f16)w2.z, (f16)w2.w,
                        (f16)w3.x, (f16)w3.y, (f16)w3.z, (f16)w3.w};
            *(f16x8*)&Bs[br][bc16]     = p0;
            *(f16x8*)&Bs[br][bc16 + 8] = p1;
        }
        __syncthreads();

        f16x8 a0 = *(const f16x8*)&As[(2 * mh)     * 16 + ln15][ln4];
        f16x8 a1 = *(const f16x8*)&As[(2 * mh + 1) * 16 + ln15][ln4];
        #pragma unroll
        for (int nj = 0; nj < 4; ++nj) {
            f16x8 bf = *(const f16x8*)&Bs[(nq * 4 + nj) * 16 + ln15][ln4];
            acc[0][nj] = __builtin_amdgcn_mfma_f32_16x16x32_f16(a0, bf, acc[0][nj], 0, 0, 0);
            acc[1][nj] = __builtin_amdgcn_mfma_f32_16x16x32_f16(a1, bf, acc[1][nj], 0, 0, 0);
        }
        __syncthreads();
    }

    #pragma unroll
    for (int mi = 0; mi < 2; ++mi)
        #pragma unroll
        for (int nj = 0; nj < 4; ++nj)
            #pragma unroll
            for (int i = 0; i < 4; ++i)
                sl[(2 * mh + mi) * 16 + (ln >> 4) * 4 + i][(nq * 4 + nj) * 16 + ln15]
                    = acc[mi][nj][i];
    __syncthreads();

    #pragma unroll
    for (int rr = 0; rr < 8; ++rr) {
        int r = wv * 8 + rr;
        int t = m0 + r;
        if (t < T_) {
            float4 v = *(const float4*)&sl[r][ln * 4];
            float mx = fmaxf(fmaxf(v.x, v.y), fmaxf(v.z, v.w));
            #pragma unroll
            for (int off = 32; off; off >>= 1) mx = fmaxf(mx, __shfl_xor(mx, off));
            float e0 = expf(v.x - mx), e1 = expf(v.y - mx);
            float e2 = expf(v.z - mx), e3 = expf(v.w - mx);
            float s = e0 + e1 + e2 + e3;
            #pragma unroll
            for (int off = 32; off; off >>= 1) s += __shfl_xor(s, off);
            float inv = 1.f / s;
            f16x4 p = {(f16)(e0 * inv), (f16)(e1 * inv), (f16)(e2 * inv), (f16)(e3 * inv)};
            *(f16x4*)(attP + ((size_t)b * T_ + t) * L_ + ln * 4) = p;
        }
    }
}

// ---------------- ctx = P @ cnn[b] (NN, fp16 MFMA; B LDS-transposed tiles)
__global__ __launch_bounds__(256) void ctx16_nn(
    const f16* __restrict__ attP,   // [B][T][L]
    const float* __restrict__ cnn,  // [B][L][H]
    float* __restrict__ ctxout)     // rows (t,b): addr b*H + t*(B*H) + col
{
    __shared__ f16 As[64][40];
    __shared__ f16 Bs[64][40];
    const int tid = threadIdx.x;
    const int m0 = blockIdx.x * 64, n0 = blockIdx.y * 64;
    const int b  = blockIdx.z;
    const int ln = tid & 63, wv = tid >> 6;
    const int ln15 = ln & 15, ln4 = (ln >> 4) * 8;
    const float* cnnb = cnn + (size_t)b * L_ * H_;
    const f16*   pb   = attP + (size_t)b * T_ * L_;
    f32x4 acc[4] = {};

    for (int kb = 0; kb < L_; kb += 32) {
        {
            int lr = tid >> 2, lc8 = (tid & 3) * 8;
            int t = m0 + lr;
            f16x8 av = {};
            if (t < T_) av = *(const f16x8*)(pb + (size_t)t * L_ + kb + lc8);
            *(f16x8*)&As[lr][lc8] = av;
        }
        {
            int br = tid >> 3;
            int nc = (tid & 7) * 8;
            const float* src = cnnb + (size_t)(kb + br) * H_ + n0 + nc;
            float4 w0 = *(const float4*)(src);
            float4 w1 = *(const float4*)(src + 4);
            float wv8[8] = {w0.x, w0.y, w0.z, w0.w, w1.x, w1.y, w1.z, w1.w};
            #pragma unroll
            for (int j = 0; j < 8; ++j) Bs[nc + j][br] = (f16)wv8[j];
        }
        __syncthreads();

        f16x8 af = *(const f16x8*)&As[wv * 16 + ln15][ln4];
        #pragma unroll
        for (int ntt = 0; ntt < 4; ++ntt) {
            f16x8 bf = *(const f16x8*)&Bs[ntt * 16 + ln15][ln4];
            acc[ntt] = __builtin_amdgcn_mfma_f32_16x16x32_f16(af, bf, acc[ntt], 0, 0, 0);
        }
        __syncthreads();
    }

    #pragma unroll
    for (int ntt = 0; ntt < 4; ++ntt)
        #pragma unroll
        for (int i = 0; i < 4; ++i) {
            int t  = m0 + wv * 16 + (ln >> 4) * 4 + i;
            int gn = n0 + ntt * 16 + ln15;
            if (t < T_)
                ctxout[(size_t)b * H_ + (size_t)t * (B_ * H_) + gn] = acc[ntt][i];
        }
}

// ---------------- per-row log_softmax over V=1000, in place
__global__ __launch_bounds__(256) void logsoftmax_k(float* __restrict__ out)
{
    const int row = blockIdx.x;
    float* p = out + (size_t)row * V_;
    const int tid = threadIdx.x, lane = tid & 63, wave = tid >> 6;
    __shared__ float red[8];

    float vals[4];
    int n = 0;
    float mx = -INFINITY;
    for (int v = tid; v < V_; v += 256) { vals[n] = p[v]; mx = fmaxf(mx, vals[n]); ++n; }
    #pragma unroll
    for (int off = 32; off; off >>= 1) mx = fmaxf(mx, __shfl_xor(mx, off));
    if (lane == 0) red[wave] = mx;
    __syncthreads();
    mx = fmaxf(fmaxf(red[0], red[1]), fmaxf(red[2], red[3]));

    float s = 0.f;
    for (int i = 0; i < n; ++i) s += expf(vals[i] - mx);
    #pragma unroll
    for (int off = 32; off; off >>= 1) s += __shfl_xor(s, off);
    if (lane == 0) red[4 + wave] = s;
    __syncthreads();
    s = red[4] + red[5] + red[6] + red[7];

    const float lse = mx + logf(s);
    n = 0;
    for (int v = tid; v < V_; v += 256) { p[v] = vals[n] - lse; ++n; }
}

extern "C" void kernel_launch(void* const* d_in, const int* in_sizes, int n_in,
                              void* d_out, int out_size, void* d_ws, size_t ws_size,
                              hipStream_t stream)
{
    const float* cnn     = (const float*)d_in[0];
    const int*   seq     = (const int*)d_in[1];
    const float* embed   = (const float*)d_in[2];
    const float* W_ih    = (const float*)d_in[3];
    const float* b_ih    = (const float*)d_in[4];
    const float* W_hh    = (const float*)d_in[5];
    const float* b_hh    = (const float*)d_in[6];
    const float* W_hm    = (const float*)d_in[7];
    const float* W_om    = (const float*)d_in[8];
    const float* W_logit = (const float*)d_in[9];
    const float* b_logit = (const float*)d_in[10];
    float* out = (float*)d_out;

    float* ws = (float*)d_ws;
    float* G    = ws;                                  // 1000*2048 = 2,048,000
    float* hbuf = G + (size_t)V_ * G4_;                // 9600*512 (rows (t,b))
    float* outv = hbuf + (size_t)B_ * T_ * H_;         // 9600*512
    ull*   xh   = (ull*)(outv + (size_t)B_ * T_ * H_); // 2*64*128 ull
    int*   tags = (int*)(xh + 2 * 64 * 128);           // 8 ints
    // scratch inside d_out (dead before the final logits write):
    float* mapped = out;                               // 9600*512 fp32; reused as ctx
    f16*   attP   = (f16*)(out + (size_t)B_ * T_ * H_); // 9600*256 fp16

    hipMemsetAsync(tags, 0, DB_ * sizeof(int), stream);

    // pregate table: G[v][:] = relu(embed[v]) @ W_ih^T + b_ih + b_hh  (fp16 MFMA)
    gemm16_nt<true, false><<<dim3(16, 32), 256, 0, stream>>>(
        embed, nullptr, W_ih, b_ih, b_hh, G, V_, G4_, E_);

    // ---- Phase 1: fence-free MFMA persistent recurrence (8 blocks) ----
    decoder_mfma<<<DB_, 512, 0, stream>>>(seq, G, W_hh, xh, tags, hbuf);

    // ---- Phase 2: batched over all 9600 (t,b) rows ----
    gemm16_nt<false, false><<<dim3(150, 8), 256, 0, stream>>>(
        hbuf, nullptr, W_hm, nullptr, nullptr, mapped, B_ * T_, H_, H_);
    score_softmax<<<dim3(3, 64), 512, 0, stream>>>(mapped, cnn, attP);
    ctx16_nn<<<dim3(3, 8, 64), 256, 0, stream>>>(attP, cnn, mapped);
    gemm16_nt<false, false><<<dim3(150, 8), 256, 0, stream>>>(
        mapped, hbuf, W_om, nullptr, nullptr, outv, B_ * T_, H_, H_);
    gemm16_nt<false, true><<<dim3(150, 16), 256, 0, stream>>>(
        outv, nullptr, W_logit, b_logit, nullptr, out, B_ * T_, V_, H_);
    logsoftmax_k<<<B_ * T_, 256, 0, stream>>>(out);
}

// Round 17
// 1020.439 us; speedup vs baseline: 1.3926x; 1.3926x over previous
//
#include <hip/hip_runtime.h>
#include <math.h>

#define B_  64
#define T_  150
#define L_  256
#define H_  512
#define E_  512
#define V_  1000
#define G4_ 2048   // 4*H
#define DB_ 16     // decoder blocks
#define HCB 32     // h-cols per decoder block (DB_*HCB == H_)

typedef _Float16 f16;
typedef f16   f16x8 __attribute__((ext_vector_type(8)));
typedef f16   f16x4 __attribute__((ext_vector_type(4)));
typedef float f32x4 __attribute__((ext_vector_type(4)));
typedef unsigned long long ull;

__device__ __forceinline__ float sigmf(float x) { return 1.0f / (1.0f + expf(-x)); }

// ---------------- fence-free persistent LSTM decoder (R11/R14, verified) ---
// Block bb owns h-cols [bb*32, bb*32+32) -> 128 gate rows. B-fragments loaded
// global->registers once (32 x f16x8). h exchange: 8B relaxed AGENT atomics
// (coherence-point, no fences). Per step: G-prefetch | poll 16 tags |
// bulk-load h (reg-staged) | MFMA | cell (4 cols/thread, direct publish) | tag.
__global__ __launch_bounds__(512) void decoder_mfma(
    const int*   __restrict__ seq,    // [B][T]
    const float* __restrict__ G,      // [V][4H] pregate table
    const float* __restrict__ Whh,    // [4H][H] fp32
    ull*  __restrict__ xh,            // [2][64][128] packed fp16 x4
    int*  __restrict__ tags,          // [16] monotone step tags
    float* __restrict__ hbuf)         // rows (t,b): [T*B][H]
{
    __shared__ f16   hlds[64][520];    // h fp16, 65 KB
    __shared__ float glds[64][132];    // gates fp32, 33.8 KB
    __shared__ float csh[64][36];      // c-state, 9.2 KB

    const int tid = threadIdx.x;
    const int bb  = blockIdx.x;
    const int ln  = tid & 63;
    const int wv  = tid >> 6;
    const int mh  = wv >> 2;           // 0..1 -> M-tiles {2mh, 2mh+1}
    const int nt2 = wv & 3;            // 0..3 -> N-tiles {2nt2, 2nt2+1}

    // ---- one-time: B fragments global -> registers (fp32 -> fp16)
    f16x8 bfr[2][16];
    #pragma unroll
    for (int j = 0; j < 2; ++j) {
        const int n = 2 * nt2 + j;
        const int grow = (n >> 1) * H_ + bb * HCB + (n & 1) * 16 + (ln & 15);
        #pragma unroll
        for (int kt = 0; kt < 16; ++kt) {
            const int k0 = kt * 32 + (ln >> 4) * 8;
            float4 w0 = *(const float4*)(Whh + (size_t)grow * H_ + k0);
            float4 w1 = *(const float4*)(Whh + (size_t)grow * H_ + k0 + 4);
            bfr[j][kt] = (f16x8){(f16)w0.x, (f16)w0.y, (f16)w0.z, (f16)w0.w,
                                 (f16)w1.x, (f16)w1.y, (f16)w1.z, (f16)w1.w};
        }
    }
    // zero hlds / csh
    for (int e = tid; e < 64 * 520 / 4; e += 512) ((ull*)hlds)[e] = 0ull;
    for (int e = tid; e < 64 * 36; e += 512) ((float*)csh)[e] = 0.f;
    __syncthreads();

    const int cb = tid >> 3, cg = tid & 7;   // cell role: b, col-quad (x8)

    for (int t = 0; t < T_; ++t) {
        // ---- G prefetch for THIS step (independent of h; hides under poll)
        const int v = seq[cb * T_ + t];
        const float* gp = G + (size_t)v * G4_ + bb * HCB + cg * 4;
        float4 gq0 = *(const float4*)(gp);
        float4 gq1 = *(const float4*)(gp + H_);
        float4 gq2 = *(const float4*)(gp + 2 * H_);
        float4 gq3 = *(const float4*)(gp + 3 * H_);

        if (t > 0) {
            if (tid < DB_) {
                while (__hip_atomic_load(&tags[tid], __ATOMIC_RELAXED,
                                         __HIP_MEMORY_SCOPE_AGENT) < t) {}
            }
            __syncthreads();
            // ---- bulk-load h^t: reg-stage 16 x 8B loads, then 8 x b128 writes
            const ull* src = xh + (size_t)(t & 1) * 64 * 128;
            ull v0[8], v1[8];
            #pragma unroll
            for (int it = 0; it < 8; ++it) {
                const int e = tid + it * 512;
                const int b = e >> 6, s = e & 63;
                v0[it] = __hip_atomic_load(&src[b * 128 + 2 * s], __ATOMIC_RELAXED,
                                           __HIP_MEMORY_SCOPE_AGENT);
                v1[it] = __hip_atomic_load(&src[b * 128 + 2 * s + 1], __ATOMIC_RELAXED,
                                           __HIP_MEMORY_SCOPE_AGENT);
            }
            #pragma unroll
            for (int it = 0; it < 8; ++it) {
                const int e = tid + it * 512;
                const int b = e >> 6, s = e & 63;
                ull* dst = (ull*)&hlds[b][s * 8];
                dst[0] = v0[it]; dst[1] = v1[it];
            }
            __syncthreads();
        }

        // ---- gate GEMM: 2 M-tiles x 2 N-tiles per wave, K=512
        f32x4 acc00 = {0.f,0.f,0.f,0.f}, acc01 = {0.f,0.f,0.f,0.f};
        f32x4 acc10 = {0.f,0.f,0.f,0.f}, acc11 = {0.f,0.f,0.f,0.f};
        #pragma unroll
        for (int kt = 0; kt < 16; ++kt) {
            const int ko = kt * 32 + (ln >> 4) * 8;
            f16x8 a0 = *(const f16x8*)&hlds[(2 * mh)     * 16 + (ln & 15)][ko];
            f16x8 a1 = *(const f16x8*)&hlds[(2 * mh + 1) * 16 + (ln & 15)][ko];
            acc00 = __builtin_amdgcn_mfma_f32_16x16x32_f16(a0, bfr[0][kt], acc00, 0, 0, 0);
            acc01 = __builtin_amdgcn_mfma_f32_16x16x32_f16(a0, bfr[1][kt], acc01, 0, 0, 0);
            acc10 = __builtin_amdgcn_mfma_f32_16x16x32_f16(a1, bfr[0][kt], acc10, 0, 0, 0);
            acc11 = __builtin_amdgcn_mfma_f32_16x16x32_f16(a1, bfr[1][kt], acc11, 0, 0, 0);
        }
        // C/D layout: col = lane&15, row = (lane>>4)*4 + reg
        {
            const int r0 = (2 * mh) * 16 + (ln >> 4) * 4;
            const int r1 = (2 * mh + 1) * 16 + (ln >> 4) * 4;
            const int c0 = (2 * nt2) * 16 + (ln & 15);
            const int c1 = (2 * nt2 + 1) * 16 + (ln & 15);
            #pragma unroll
            for (int i = 0; i < 4; ++i) {
                glds[r0 + i][c0] = acc00[i];
                glds[r0 + i][c1] = acc01[i];
                glds[r1 + i][c0] = acc10[i];
                glds[r1 + i][c1] = acc11[i];
            }
        }
        __syncthreads();

        // ---- cell: thread (cb, cols cg*4..cg*4+3); publish directly
        {
            float4 Gi = *(const float4*)&glds[cb][cg * 4];
            float4 Gf = *(const float4*)&glds[cb][32 + cg * 4];
            float4 Gg = *(const float4*)&glds[cb][64 + cg * 4];
            float4 Go = *(const float4*)&glds[cb][96 + cg * 4];
            float4 cold = *(const float4*)&csh[cb][cg * 4];
            float gi[4] = {Gi.x + gq0.x, Gi.y + gq0.y, Gi.z + gq0.z, Gi.w + gq0.w};
            float gf[4] = {Gf.x + gq1.x, Gf.y + gq1.y, Gf.z + gq1.z, Gf.w + gq1.w};
            float gg[4] = {Gg.x + gq2.x, Gg.y + gq2.y, Gg.z + gq2.z, Gg.w + gq2.w};
            float go[4] = {Go.x + gq3.x, Go.y + gq3.y, Go.z + gq3.z, Go.w + gq3.w};
            float cl[4] = {cold.x, cold.y, cold.z, cold.w};
            float4 cnew, hnew;
            f16x4 hp;
            #pragma unroll
            for (int i = 0; i < 4; ++i) {
                float c2 = sigmf(gf[i]) * cl[i] + sigmf(gi[i]) * tanhf(gg[i]);
                float h2 = sigmf(go[i]) * tanhf(c2);
                ((float*)&cnew)[i] = c2;
                ((float*)&hnew)[i] = h2;
                hp[i] = (f16)h2;
            }
            *(float4*)&csh[cb][cg * 4] = cnew;
            *(float4*)&hbuf[((size_t)t * 64 + cb) * H_ + bb * HCB + cg * 4] = hnew;
            __hip_atomic_store(
                &xh[(size_t)((t + 1) & 1) * 64 * 128 + cb * 128 + bb * 8 + cg],
                __builtin_bit_cast(ull, hp),
                __ATOMIC_RELAXED, __HIP_MEMORY_SCOPE_AGENT);
        }
        __syncthreads();   // compiler drains vmcnt before s_barrier
        if (tid == 0)
            __hip_atomic_store(&tags[bb], t + 1, __ATOMIC_RELAXED,
                               __HIP_MEMORY_SCOPE_AGENT);
    }
}

// ---------------- fp16-MFMA NT GEMM: C[M][N] = op([A1|A2])[M][K] @ Bm[N][K]^T
template<bool RELU_A, bool REMAP>
__global__ __launch_bounds__(256) void gemm16_nt(
    const float* __restrict__ A1, const float* __restrict__ A2,
    const float* __restrict__ Bm,
    const float* __restrict__ bias1, const float* __restrict__ bias2,
    float* __restrict__ C, int M, int N, int KA)
{
    __shared__ f16 As[64][40];
    __shared__ f16 Bs[64][40];
    const int tid = threadIdx.x;
    const int m0 = blockIdx.x * 64, n0 = blockIdx.y * 64;
    const int ln = tid & 63, wv = tid >> 6;
    const int lr = tid >> 2, lc8 = (tid & 3) * 8;
    const int K = A2 ? 2 * KA : KA;
    f32x4 acc[4] = {};

    for (int kb = 0; kb < K; kb += 32) {
        const float* Ap; int kk;
        if (kb < KA) { Ap = A1; kk = kb; } else { Ap = A2; kk = kb - KA; }
        int gm = m0 + lr;
        float4 a0 = make_float4(0.f, 0.f, 0.f, 0.f), a1 = a0;
        if (gm < M) {
            a0 = *(const float4*)(Ap + (size_t)gm * KA + kk + lc8);
            a1 = *(const float4*)(Ap + (size_t)gm * KA + kk + lc8 + 4);
        }
        if (RELU_A) {
            a0.x = fmaxf(a0.x, 0.f); a0.y = fmaxf(a0.y, 0.f);
            a0.z = fmaxf(a0.z, 0.f); a0.w = fmaxf(a0.w, 0.f);
            a1.x = fmaxf(a1.x, 0.f); a1.y = fmaxf(a1.y, 0.f);
            a1.z = fmaxf(a1.z, 0.f); a1.w = fmaxf(a1.w, 0.f);
        }
        f16x8 av = {(f16)a0.x, (f16)a0.y, (f16)a0.z, (f16)a0.w,
                    (f16)a1.x, (f16)a1.y, (f16)a1.z, (f16)a1.w};
        *(f16x8*)&As[lr][lc8] = av;

        int gn = n0 + lr;
        float4 b0 = make_float4(0.f, 0.f, 0.f, 0.f), b1 = b0;
        if (gn < N) {
            b0 = *(const float4*)(Bm + (size_t)gn * K + kb + lc8);
            b1 = *(const float4*)(Bm + (size_t)gn * K + kb + lc8 + 4);
        }
        f16x8 bv = {(f16)b0.x, (f16)b0.y, (f16)b0.z, (f16)b0.w,
                    (f16)b1.x, (f16)b1.y, (f16)b1.z, (f16)b1.w};
        *(f16x8*)&Bs[lr][lc8] = bv;
        __syncthreads();

        f16x8 af = *(const f16x8*)&As[wv * 16 + (ln & 15)][(ln >> 4) * 8];
        #pragma unroll
        for (int ntt = 0; ntt < 4; ++ntt) {
            f16x8 bf = *(const f16x8*)&Bs[ntt * 16 + (ln & 15)][(ln >> 4) * 8];
            acc[ntt] = __builtin_amdgcn_mfma_f32_16x16x32_f16(af, bf, acc[ntt], 0, 0, 0);
        }
        __syncthreads();
    }

    #pragma unroll
    for (int ntt = 0; ntt < 4; ++ntt)
        #pragma unroll
        for (int i = 0; i < 4; ++i) {
            int gm = m0 + wv * 16 + (ln >> 4) * 4 + i;
            int gn = n0 + ntt * 16 + (ln & 15);
            if (gm < M && gn < N) {
                float v = acc[ntt][i];
                if (bias1) v += bias1[gn];
                if (bias2) v += bias2[gn];
                size_t row = REMAP ? ((size_t)(gm & 63) * T_ + (gm >> 6)) : (size_t)gm;
                C[row * (size_t)N + gn] = v;
            }
        }
}

// ---------------- fused score GEMM + softmax: per (t-chunk, b)
// S[64][256] = mapped_rows @ cnn[b]^T (fp16 MFMA), row-softmax, write P fp16.
__global__ __launch_bounds__(512) void score_softmax(
    const float* __restrict__ mapped,  // rows (t,b), stride H
    const float* __restrict__ cnn,     // [B][L][H]
    f16* __restrict__ attP)            // [B][T][L] fp16 probabilities
{
    __shared__ f16   As[64][40];
    __shared__ f16   Bs[256][40];
    __shared__ float sl[64][260];

    const int tid = threadIdx.x;
    const int m0  = blockIdx.x * 64;
    const int b   = blockIdx.y;
    const int ln  = tid & 63, wv = tid >> 6;
    const int mh  = wv >> 2, nq = wv & 3;     // 2 M-tiles x 4 N-tiles per wave
    const int ln15 = ln & 15, ln4 = (ln >> 4) * 8;
    const float* cnnb = cnn + (size_t)b * L_ * H_;

    f32x4 acc[2][4] = {};

    for (int kb = 0; kb < H_; kb += 32) {
        // stage A: rows t = m0+lr (cast fp16)
        {
            int lr = tid >> 3, lc4 = (tid & 7) * 4;
            int t = m0 + lr;
            float4 a = make_float4(0.f, 0.f, 0.f, 0.f);
            if (t < T_) a = *(const float4*)(mapped + ((size_t)t * 64 + b) * H_ + kb + lc4);
            As[lr][lc4 + 0] = (f16)a.x; As[lr][lc4 + 1] = (f16)a.y;
            As[lr][lc4 + 2] = (f16)a.z; As[lr][lc4 + 3] = (f16)a.w;
        }
        // stage B: all 256 L-rows x 32 k
        {
            int br = tid >> 1, bc16 = (tid & 1) * 16;
            const float* src = cnnb + (size_t)br * H_ + kb + bc16;
            float4 w0 = *(const float4*)(src);
            float4 w1 = *(const float4*)(src + 4);
            float4 w2 = *(const float4*)(src + 8);
            float4 w3 = *(const float4*)(src + 12);
            f16x8 p0 = {(f16)w0.x, (f16)w0.y, (f16)w0.z, (f16)w0.w,
                        (f16)w1.x, (f16)w1.y, (f16)w1.z, (f16)w1.w};
            f16x8 p1 = {(f16)w2.x, (f16)w2.y, (f16)w2.z, (f16)w2.w,
                        (f16)w3.x, (f16)w3.y, (f16)w3.z, (f16)w3.w};
            *(f16x8*)&Bs[br][bc16]     = p0;
            *(f16x8*)&Bs[br][bc16 + 8] = p1;
        }
        __syncthreads();

        f16x8 a0 = *(const f16x8*)&As[(2 * mh)     * 16 + ln15][ln4];
        f16x8 a1 = *(const f16x8*)&As[(2 * mh + 1) * 16 + ln15][ln4];
        #pragma unroll
        for (int nj = 0; nj < 4; ++nj) {
            f16x8 bf = *(const f16x8*)&Bs[(nq * 4 + nj) * 16 + ln15][ln4];
            acc[0][nj] = __builtin_amdgcn_mfma_f32_16x16x32_f16(a0, bf, acc[0][nj], 0, 0, 0);
            acc[1][nj] = __builtin_amdgcn_mfma_f32_16x16x32_f16(a1, bf, acc[1][nj], 0, 0, 0);
        }
        __syncthreads();
    }

    // scatter S to sl
    #pragma unroll
    for (int mi = 0; mi < 2; ++mi)
        #pragma unroll
        for (int nj = 0; nj < 4; ++nj)
            #pragma unroll
            for (int i = 0; i < 4; ++i)
                sl[(2 * mh + mi) * 16 + (ln >> 4) * 4 + i][(nq * 4 + nj) * 16 + ln15]
                    = acc[mi][nj][i];
    __syncthreads();

    // softmax: 8 rows per wave
    #pragma unroll
    for (int rr = 0; rr < 8; ++rr) {
        int r = wv * 8 + rr;
        int t = m0 + r;
        if (t < T_) {
            float4 v = *(const float4*)&sl[r][ln * 4];
            float mx = fmaxf(fmaxf(v.x, v.y), fmaxf(v.z, v.w));
            #pragma unroll
            for (int off = 32; off; off >>= 1) mx = fmaxf(mx, __shfl_xor(mx, off));
            float e0 = expf(v.x - mx), e1 = expf(v.y - mx);
            float e2 = expf(v.z - mx), e3 = expf(v.w - mx);
            float s = e0 + e1 + e2 + e3;
            #pragma unroll
            for (int off = 32; off; off >>= 1) s += __shfl_xor(s, off);
            float inv = 1.f / s;
            f16x4 p = {(f16)(e0 * inv), (f16)(e1 * inv), (f16)(e2 * inv), (f16)(e3 * inv)};
            *(f16x4*)(attP + ((size_t)b * T_ + t) * L_ + ln * 4) = p;
        }
    }
}

// ---------------- ctx = P @ cnn[b] (NN, fp16 MFMA; B LDS-transposed tiles)
__global__ __launch_bounds__(256) void ctx16_nn(
    const f16* __restrict__ attP,   // [B][T][L]
    const float* __restrict__ cnn,  // [B][L][H]
    float* __restrict__ ctxout)     // rows (t,b): addr b*H + t*(B*H) + col
{
    __shared__ f16 As[64][40];
    __shared__ f16 Bs[64][40];
    const int tid = threadIdx.x;
    const int m0 = blockIdx.x * 64, n0 = blockIdx.y * 64;
    const int b  = blockIdx.z;
    const int ln = tid & 63, wv = tid >> 6;
    const int ln15 = ln & 15, ln4 = (ln >> 4) * 8;
    const float* cnnb = cnn + (size_t)b * L_ * H_;
    const f16*   pb   = attP + (size_t)b * T_ * L_;
    f32x4 acc[4] = {};

    for (int kb = 0; kb < L_; kb += 32) {
        // stage A: fp16 P rows t = m0+lr
        {
            int lr = tid >> 2, lc8 = (tid & 3) * 8;
            int t = m0 + lr;
            f16x8 av = {};
            if (t < T_) av = *(const f16x8*)(pb + (size_t)t * L_ + kb + lc8);
            *(f16x8*)&As[lr][lc8] = av;
        }
        // stage B transposed: Bs[n][k] = cnn[b][kb+k][n0+n]
        {
            int br = tid >> 3;              // k-row 0..31
            int nc = (tid & 7) * 8;         // n-group
            const float* src = cnnb + (size_t)(kb + br) * H_ + n0 + nc;
            float4 w0 = *(const float4*)(src);
            float4 w1 = *(const float4*)(src + 4);
            float wv8[8] = {w0.x, w0.y, w0.z, w0.w, w1.x, w1.y, w1.z, w1.w};
            #pragma unroll
            for (int j = 0; j < 8; ++j) Bs[nc + j][br] = (f16)wv8[j];
        }
        __syncthreads();

        f16x8 af = *(const f16x8*)&As[wv * 16 + ln15][ln4];
        #pragma unroll
        for (int ntt = 0; ntt < 4; ++ntt) {
            f16x8 bf = *(const f16x8*)&Bs[ntt * 16 + ln15][ln4];
            acc[ntt] = __builtin_amdgcn_mfma_f32_16x16x32_f16(af, bf, acc[ntt], 0, 0, 0);
        }
        __syncthreads();
    }

    #pragma unroll
    for (int ntt = 0; ntt < 4; ++ntt)
        #pragma unroll
        for (int i = 0; i < 4; ++i) {
            int t  = m0 + wv * 16 + (ln >> 4) * 4 + i;
            int gn = n0 + ntt * 16 + ln15;
            if (t < T_)
                ctxout[(size_t)b * H_ + (size_t)t * (B_ * H_) + gn] = acc[ntt][i];
        }
}

// ---------------- per-row log_softmax over V=1000, in place
__global__ __launch_bounds__(256) void logsoftmax_k(float* __restrict__ out)
{
    const int row = blockIdx.x;
    float* p = out + (size_t)row * V_;
    const int tid = threadIdx.x, lane = tid & 63, wave = tid >> 6;
    __shared__ float red[8];

    float vals[4];
    int n = 0;
    float mx = -INFINITY;
    for (int v = tid; v < V_; v += 256) { vals[n] = p[v]; mx = fmaxf(mx, vals[n]); ++n; }
    #pragma unroll
    for (int off = 32; off; off >>= 1) mx = fmaxf(mx, __shfl_xor(mx, off));
    if (lane == 0) red[wave] = mx;
    __syncthreads();
    mx = fmaxf(fmaxf(red[0], red[1]), fmaxf(red[2], red[3]));

    float s = 0.f;
    for (int i = 0; i < n; ++i) s += expf(vals[i] - mx);
    #pragma unroll
    for (int off = 32; off; off >>= 1) s += __shfl_xor(s, off);
    if (lane == 0) red[4 + wave] = s;
    __syncthreads();
    s = red[4] + red[5] + red[6] + red[7];

    const float lse = mx + logf(s);
    n = 0;
    for (int v = tid; v < V_; v += 256) { p[v] = vals[n] - lse; ++n; }
}

extern "C" void kernel_launch(void* const* d_in, const int* in_sizes, int n_in,
                              void* d_out, int out_size, void* d_ws, size_t ws_size,
                              hipStream_t stream)
{
    const float* cnn     = (const float*)d_in[0];
    const int*   seq     = (const int*)d_in[1];
    const float* embed   = (const float*)d_in[2];
    const float* W_ih    = (const float*)d_in[3];
    const float* b_ih    = (const float*)d_in[4];
    const float* W_hh    = (const float*)d_in[5];
    const float* b_hh    = (const float*)d_in[6];
    const float* W_hm    = (const float*)d_in[7];
    const float* W_om    = (const float*)d_in[8];
    const float* W_logit = (const float*)d_in[9];
    const float* b_logit = (const float*)d_in[10];
    float* out = (float*)d_out;

    float* ws = (float*)d_ws;
    float* G    = ws;                                  // 1000*2048 = 2,048,000
    float* hbuf = G + (size_t)V_ * G4_;                // 9600*512 (rows (t,b))
    float* outv = hbuf + (size_t)B_ * T_ * H_;         // 9600*512
    ull*   xh   = (ull*)(outv + (size_t)B_ * T_ * H_); // 2*64*128 ull
    int*   tags = (int*)(xh + 2 * 64 * 128);           // 16 ints
    // scratch inside d_out (dead before the final logits write):
    float* mapped = out;                               // 9600*512 fp32; reused as ctx
    f16*   attP   = (f16*)(out + (size_t)B_ * T_ * H_); // 9600*256 fp16

    hipMemsetAsync(tags, 0, DB_ * sizeof(int), stream);

    // pregate table: G[v][:] = relu(embed[v]) @ W_ih^T + b_ih + b_hh  (fp16 MFMA)
    gemm16_nt<true, false><<<dim3(16, 32), 256, 0, stream>>>(
        embed, nullptr, W_ih, b_ih, b_hh, G, V_, G4_, E_);

    // ---- Phase 1: fence-free MFMA persistent recurrence (16 blocks) ----
    decoder_mfma<<<DB_, 512, 0, stream>>>(seq, G, W_hh, xh, tags, hbuf);

    // ---- Phase 2: batched over all 9600 (t,b) rows ----
    // mapped = h @ W_hm^T   (fp16 MFMA)
    gemm16_nt<false, false><<<dim3(150, 8), 256, 0, stream>>>(
        hbuf, nullptr, W_hm, nullptr, nullptr, mapped, B_ * T_, H_, H_);
    // fused: S = mapped @ cnn[b]^T, softmax -> P fp16
    score_softmax<<<dim3(3, 64), 512, 0, stream>>>(mapped, cnn, attP);
    // ctx = P @ cnn[b]   (fp16 MFMA; overwrites mapped)
    ctx16_nn<<<dim3(3, 8, 64), 256, 0, stream>>>(attP, cnn, mapped);
    // out = [ctx | h] @ W_om^T   (fp16 MFMA, fused K=1024)
    gemm16_nt<false, false><<<dim3(150, 8), 256, 0, stream>>>(
        mapped, hbuf, W_om, nullptr, nullptr, outv, B_ * T_, H_, H_);
    // logits (+bias), remap rows (t,b) -> (b,t)   (fp16 MFMA)
    gemm16_nt<false, true><<<dim3(150, 16), 256, 0, stream>>>(
        outv, nullptr, W_logit, b_logit, nullptr, out, B_ * T_, V_, H_);
    logsoftmax_k<<<B_ * T_, 256, 0, stream>>>(out);
}